// Round 2
// baseline (762.207 us; speedup 1.0000x reference)
//
#include <hip/hip_runtime.h>
#include <hip/hip_bf16.h>
#include <stdint.h>

#define B_ 4
#define S_ 2048
#define D_ 1024
#define H_ 4
#define DH_ 256

typedef __bf16 bf16x8 __attribute__((ext_vector_type(8)));
typedef float f32x4 __attribute__((ext_vector_type(4)));

#define MFMA16(a, b, c) __builtin_amdgcn_mfma_f32_16x16x32_bf16(a, b, c, 0, 0, 0)

typedef __attribute__((address_space(1))) const unsigned int gu32;
typedef __attribute__((address_space(3))) unsigned int lu32;
#define GLD16(g, l) __builtin_amdgcn_global_load_lds((gu32*)(g), (lu32*)(l), 16, 0, 0)

__device__ __forceinline__ short f2bf(float f) {
    __bf16 h = (__bf16)f;
    return __builtin_bit_cast(short, h);
}

// ---------------- fp32 -> bf16 convert (vectorized) ----------------
__global__ void cvt_kernel(const float* __restrict__ src, short* __restrict__ dst, int n4) {
    int i = blockIdx.x * blockDim.x + threadIdx.x;
    if (i >= n4) return;
    float4 f = ((const float4*)src)[i];
    short4 o;
    o.x = f2bf(f.x); o.y = f2bf(f.y); o.z = f2bf(f.z); o.w = f2bf(f.w);
    ((short4*)dst)[i] = o;
}

// ---------------- generic B^T GEMM: C = A * B^T (+bias, per-mode epilogue) ---
// A: [M x K] row-major (lda), Bw: [N x K] row-major (ldb). 128x128 tile, BK=64.
// MODE 0: qs  = (A*W^T + qb)/16 -> bf16 [B,H,S,DH]   (1/sqrt(DH) folded in)
// MODE 1: ks  = (A*W^T + kb)    -> bf16 [B,H,S,DH]
// MODE 2: vsT = (vW*v^T + vb[row]) -> bf16 [B,DH,S]
// MODE 3: out = A*W^T (f32) -> d_out [B,S,D]
template<int MODE>
__global__ __launch_bounds__(256)
void gemm_bt(const short* __restrict__ A, long sA, int lda,
             const short* __restrict__ Bw, long sB, int ldb,
             const float* __restrict__ bias,
             void* __restrict__ outp, int K) {
    __shared__ short Ash[128 * 64];
    __shared__ short Bsh[128 * 64];
    const int tid = threadIdx.x, wid = tid >> 6, lane = tid & 63;
    const int bz = blockIdx.z;
    const int tile_m = blockIdx.y * 128, tile_n = blockIdx.x * 128;
    const short* Ab = A + (long)bz * sA + (long)tile_m * lda;
    const short* Bb = Bw + (long)bz * sB + (long)tile_n * ldb;
    const int wr = wid >> 1, wc = wid & 1;

    f32x4 acc[4][4];
#pragma unroll
    for (int i = 0; i < 4; i++)
#pragma unroll
        for (int j = 0; j < 4; j++) acc[i][j] = {0.f, 0.f, 0.f, 0.f};

    for (int k0 = 0; k0 < K; k0 += 64) {
        __syncthreads();
#pragma unroll
        for (int i = 0; i < 4; i++) {
            int off = ((i * 4 + wid) * 64 + lane) * 16;  // byte offset in 16KB tile
            int row = off >> 7;
            int col = (off & 127) >> 1;  // element col
            GLD16(Ab + row * lda + k0 + col, ((char*)Ash) + off);
            GLD16(Bb + row * ldb + k0 + col, ((char*)Bsh) + off);
        }
        __syncthreads();
#pragma unroll
        for (int kk = 0; kk < 2; kk++) {
            bf16x8 af[4], bfr[4];
#pragma unroll
            for (int mi = 0; mi < 4; mi++)
                af[mi] = *(const bf16x8*)&Ash[(wr * 64 + mi * 16 + (lane & 15)) * 64 + kk * 32 + (lane >> 4) * 8];
#pragma unroll
            for (int ni = 0; ni < 4; ni++)
                bfr[ni] = *(const bf16x8*)&Bsh[(wc * 64 + ni * 16 + (lane & 15)) * 64 + kk * 32 + (lane >> 4) * 8];
#pragma unroll
            for (int mi = 0; mi < 4; mi++)
#pragma unroll
                for (int ni = 0; ni < 4; ni++)
                    acc[mi][ni] = MFMA16(af[mi], bfr[ni], acc[mi][ni]);
        }
    }
#pragma unroll
    for (int mi = 0; mi < 4; mi++)
#pragma unroll
        for (int ni = 0; ni < 4; ni++)
#pragma unroll
            for (int j = 0; j < 4; j++) {
                int r = tile_m + wr * 64 + mi * 16 + (lane >> 4) * 4 + j;
                int c = tile_n + wc * 64 + ni * 16 + (lane & 15);
                float v = acc[mi][ni][j];
                if (MODE == 0) {
                    v = (v + bias[c]) * 0.0625f;
                    ((short*)outp)[(((long)bz * H_ + (c >> 8)) * S_ + r) * DH_ + (c & 255)] = f2bf(v);
                } else if (MODE == 1) {
                    v += bias[c];
                    ((short*)outp)[(((long)bz * H_ + (c >> 8)) * S_ + r) * DH_ + (c & 255)] = f2bf(v);
                } else if (MODE == 2) {
                    v += bias[r];
                    ((short*)outp)[((long)bz * DH_ + r) * S_ + c] = f2bf(v);
                } else {
                    ((float*)outp)[((long)bz * S_ + r) * D_ + c] = v;
                }
            }
}

// ---------------- pass 1: raw logits -> d_out attn region + row stats -------
// block: 512 thr = 8 waves, (wr 0..3: 32 rows, wc 0..1: 64 cols per 128-chunk)
__global__ __launch_bounds__(512)
void attn_logits(const short* __restrict__ qsc, const short* __restrict__ ksc,
                 float* __restrict__ attnp, float* __restrict__ rowm,
                 float* __restrict__ rowsum) {
    __shared__ short Bsh[8 * 128 * 32];  // 64KB: [kk][t:128][k:32]
    __shared__ float sm[2][128], ssm[2][128];
    const int tid = threadIdx.x, wid = tid >> 6, lane = tid & 63;
    const int bh = blockIdx.x;
    const int b = bh >> 2, h = bh & 3;
    const int sg = blockIdx.y * 128;
    const int wr = wid >> 1, wc = wid & 1;
    const short* qbase = qsc + (((long)b * H_ + h) * S_ + sg) * DH_;
    const short* kbase = ksc + (((long)b * H_ + h) * S_) * DH_;
    float* attnbase = attnp + ((long)(b * S_ + sg) * H_ + h) * S_;

    // ---- Q tile -> registers, staged in 4 chunks through Bsh's first 16KB ----
    bf16x8 qf[2][8];
    short* Ash = Bsh;
    for (int c = 0; c < 4; c++) {
        __syncthreads();
#pragma unroll
        for (int i = 0; i < 2; i++) {
            int off = ((i * 8 + wid) * 64 + lane) * 16;  // 0..16383
            int row = off >> 7;
            int col = (off & 127) >> 1;
            GLD16(qbase + row * DH_ + c * 64 + col, ((char*)Ash) + off);
        }
        __syncthreads();
#pragma unroll
        for (int mi = 0; mi < 2; mi++)
#pragma unroll
            for (int cc = 0; cc < 2; cc++)
                qf[mi][c * 2 + cc] =
                    *(const bf16x8*)&Ash[(wr * 32 + mi * 16 + (lane & 15)) * 64 + cc * 32 + (lane >> 4) * 8];
    }

    float mrun[8], srun[8];
#pragma unroll
    for (int i = 0; i < 8; i++) { mrun[i] = -1e30f; srun[i] = 0.f; }

    for (int tc = 0; tc < 16; tc++) {
        __syncthreads();
        // stage K tile [128 t x 256 k], sub-tiled by kk (rows of 64B -> 8-way max)
#pragma unroll
        for (int i = 0; i < 8; i++) {
            int off = ((i * 8 + wid) * 64 + lane) * 16;  // 0..65535 bytes
            int e = off >> 1;
            int kk = e >> 12, rem = e & 4095;
            int t = rem >> 5, kc = rem & 31;
            GLD16(kbase + (long)(tc * 128 + t) * DH_ + kk * 32 + kc, ((char*)Bsh) + off);
        }
        __syncthreads();
        f32x4 acc[2][4];
#pragma unroll
        for (int mi = 0; mi < 2; mi++)
#pragma unroll
            for (int ni = 0; ni < 4; ni++) acc[mi][ni] = {0.f, 0.f, 0.f, 0.f};
#pragma unroll
        for (int kk = 0; kk < 8; kk++) {
            bf16x8 bfr[4];
#pragma unroll
            for (int ni = 0; ni < 4; ni++)
                bfr[ni] = *(const bf16x8*)&Bsh[kk * 4096 + (wc * 64 + ni * 16 + (lane & 15)) * 32 + (lane >> 4) * 8];
#pragma unroll
            for (int mi = 0; mi < 2; mi++)
#pragma unroll
                for (int ni = 0; ni < 4; ni++)
                    acc[mi][ni] = MFMA16(qf[mi][kk], bfr[ni], acc[mi][ni]);
        }
        // online stats (raw logits stay raw; only the scalar sum is rescaled)
#pragma unroll
        for (int mi = 0; mi < 2; mi++)
#pragma unroll
            for (int j = 0; j < 4; j++) {
                float tmax = -1e30f;
#pragma unroll
                for (int ni = 0; ni < 4; ni++) tmax = fmaxf(tmax, acc[mi][ni][j]);
#pragma unroll
                for (int m = 1; m < 16; m <<= 1) tmax = fmaxf(tmax, __shfl_xor(tmax, m, 64));
                float mn = fmaxf(mrun[mi * 4 + j], tmax);
                float ps = 0.f;
#pragma unroll
                for (int ni = 0; ni < 4; ni++) ps += __expf(acc[mi][ni][j] - mn);
#pragma unroll
                for (int m = 1; m < 16; m <<= 1) ps += __shfl_xor(ps, m, 64);
                srun[mi * 4 + j] = srun[mi * 4 + j] * __expf(mrun[mi * 4 + j] - mn) + ps;
                mrun[mi * 4 + j] = mn;
            }
        // store raw logits to d_out attn region ([B,S,H,T] layout)
#pragma unroll
        for (int mi = 0; mi < 2; mi++)
#pragma unroll
            for (int ni = 0; ni < 4; ni++)
#pragma unroll
                for (int j = 0; j < 4; j++) {
                    int r = wr * 32 + mi * 16 + (lane >> 4) * 4 + j;
                    int t = tc * 128 + wc * 64 + ni * 16 + (lane & 15);
                    attnbase[(long)r * (H_ * S_) + t] = acc[mi][ni][j];
                }
    }
    // merge the two wc halves' stats
    __syncthreads();
    if ((lane & 15) == 0) {
#pragma unroll
        for (int mi = 0; mi < 2; mi++)
#pragma unroll
            for (int j = 0; j < 4; j++) {
                int r = wr * 32 + mi * 16 + (lane >> 4) * 4 + j;
                sm[wc][r] = mrun[mi * 4 + j];
                ssm[wc][r] = srun[mi * 4 + j];
            }
    }
    __syncthreads();
    if (tid < 128) {
        float m0 = sm[0][tid], m1 = sm[1][tid];
        float mm = fmaxf(m0, m1);
        float sv = ssm[0][tid] * __expf(m0 - mm) + ssm[1][tid] * __expf(m1 - mm);
        long ridx = ((long)b * H_ + h) * S_ + sg + tid;
        rowm[ridx] = mm;
        rowsum[ridx] = sv;
    }
}

// ---------------- pass 2: normalize probs in-place + PV MFMA ----------------
// block: 512 thr = 8 waves, (wr 0..1: 64 rows, wc 0..3: 64 e-cols)
__global__ __launch_bounds__(512)
void attn_pv(float* __restrict__ attnp, const short* __restrict__ vsT,
             const float* __restrict__ rowm, const float* __restrict__ rowsum,
             float* __restrict__ headb) {
    __shared__ short Pl[128 * 64];   // 16KB
    __shared__ short Vsh[256 * 64];  // 32KB
    __shared__ float lm[128], li[128];
    const int tid = threadIdx.x, wid = tid >> 6, lane = tid & 63;
    const int bh = blockIdx.x;
    const int b = bh >> 2, h = bh & 3;
    const int sg = blockIdx.y * 128;
    const int wr = wid >> 2, wc = wid & 3;
    float* attnbase = attnp + ((long)(b * S_ + sg) * H_ + h) * S_;
    const short* vbase = vsT + (long)b * DH_ * S_;

    if (tid < 128) {
        long ridx = ((long)b * H_ + h) * S_ + sg + tid;
        lm[tid] = rowm[ridx];
        li[tid] = 1.f / rowsum[ridx];
    }
    __syncthreads();

    f32x4 acc[4][4];
#pragma unroll
    for (int i = 0; i < 4; i++)
#pragma unroll
        for (int j = 0; j < 4; j++) acc[i][j] = {0.f, 0.f, 0.f, 0.f};

    const int prow0 = tid >> 4, pf4 = tid & 15;
    for (int tc = 0; tc < 32; tc++) {
        // normalize logits -> probs for ALL 128 rows (4 rows per thread),
        // write probs back in place (d_out attn region) and bf16 into Pl
#pragma unroll
        for (int rr = 0; rr < 4; rr++) {
            int prow = prow0 + rr * 32;
            float* gp = attnbase + (long)prow * (H_ * S_) + tc * 64 + pf4 * 4;
            float4 x = *(const float4*)gp;
            float mm = lm[prow], ii = li[prow];
            float4 p;
            p.x = __expf(x.x - mm) * ii;
            p.y = __expf(x.y - mm) * ii;
            p.z = __expf(x.z - mm) * ii;
            p.w = __expf(x.w - mm) * ii;
            *(float4*)gp = p;
            short4 pb;
            pb.x = f2bf(p.x); pb.y = f2bf(p.y); pb.z = f2bf(p.z); pb.w = f2bf(p.w);
            *(short4*)&Pl[prow * 64 + pf4 * 4] = pb;
        }
        // stage V tile [256 e x 64 t]
#pragma unroll
        for (int i = 0; i < 4; i++) {
            int off = ((i * 8 + wid) * 64 + lane) * 16;  // 0..32767
            int e = off >> 1;
            int row = e >> 6, kc = e & 63;
            GLD16(vbase + (long)row * S_ + tc * 64 + kc, ((char*)Vsh) + off);
        }
        __syncthreads();
#pragma unroll
        for (int kk = 0; kk < 2; kk++) {
            bf16x8 af[4], bfr[4];
#pragma unroll
            for (int mi = 0; mi < 4; mi++)
                af[mi] = *(const bf16x8*)&Pl[(wr * 64 + mi * 16 + (lane & 15)) * 64 + kk * 32 + (lane >> 4) * 8];
#pragma unroll
            for (int ni = 0; ni < 4; ni++)
                bfr[ni] = *(const bf16x8*)&Vsh[(wc * 64 + ni * 16 + (lane & 15)) * 64 + kk * 32 + (lane >> 4) * 8];
#pragma unroll
            for (int mi = 0; mi < 4; mi++)
#pragma unroll
                for (int ni = 0; ni < 4; ni++)
                    acc[mi][ni] = MFMA16(af[mi], bfr[ni], acc[mi][ni]);
        }
        __syncthreads();
    }
#pragma unroll
    for (int mi = 0; mi < 4; mi++)
#pragma unroll
        for (int ni = 0; ni < 4; ni++)
#pragma unroll
            for (int j = 0; j < 4; j++) {
                int r = wr * 64 + mi * 16 + (lane >> 4) * 4 + j;
                int c = wc * 64 + ni * 16 + (lane & 15);
                headb[(((long)b * H_ + h) * S_ + sg + r) * DH_ + c] = acc[mi][ni][j];
            }
}

// ---------------- head mean over H -> bf16 ----------------
__global__ void head_reduce(const float* __restrict__ headb, short* __restrict__ hmean, int n4) {
    int i = blockIdx.x * blockDim.x + threadIdx.x;
    if (i >= n4) return;
    long f = (long)i * 4;
    int e = (int)(f & (DH_ - 1));
    long bs = f >> 8;
    int b = (int)(bs >> 11), s = (int)(bs & (S_ - 1));
    float4 sum = {0.f, 0.f, 0.f, 0.f};
#pragma unroll
    for (int h = 0; h < H_; h++) {
        float4 a = *(const float4*)&headb[(((long)b * H_ + h) * S_ + s) * DH_ + e];
        sum.x += a.x; sum.y += a.y; sum.z += a.z; sum.w += a.w;
    }
    short4 o;
    o.x = f2bf(sum.x * 0.25f); o.y = f2bf(sum.y * 0.25f);
    o.z = f2bf(sum.z * 0.25f); o.w = f2bf(sum.w * 0.25f);
    *(short4*)&hmean[f] = o;
}

extern "C" void kernel_launch(void* const* d_in, const int* in_sizes, int n_in,
                              void* d_out, int out_size, void* d_ws, size_t ws_size,
                              hipStream_t stream) {
    (void)in_sizes; (void)n_in; (void)out_size; (void)ws_size;
    const float* q = (const float*)d_in[0];
    const float* k = (const float*)d_in[1];
    const float* v = (const float*)d_in[2];
    const float* vW = (const float*)d_in[3];
    const float* vb = (const float*)d_in[4];
    const float* qW = (const float*)d_in[5];
    const float* qb = (const float*)d_in[6];
    const float* kW = (const float*)d_in[7];
    const float* kb = (const float*)d_in[8];
    const float* wH = (const float*)d_in[9];

    long off = 0;
    char* base = (char*)d_ws;
    auto alloc = [&](long bytes) {
        char* p = base + off;
        off = (off + bytes + 255) & ~255L;
        return p;
    };
    // live through attention:
    short* q_bf = (short*)alloc((long)B_ * S_ * D_ * 2);   // dead after gemm<0>; reused by headb
    short* k_bf = (short*)alloc((long)B_ * S_ * D_ * 2);   // dead after gemm<1>; reused by headb
    short* v_bf = (short*)alloc((long)B_ * S_ * D_ * 2);   // dead after gemm<2>; reused by hmean
    short* wq_bf = (short*)alloc((long)H_ * DH_ * D_ * 2);
    short* wk_bf = (short*)alloc((long)H_ * DH_ * D_ * 2);
    short* wv_bf = (short*)alloc((long)DH_ * D_ * 2);
    short* wh_bf = (short*)alloc((long)D_ * DH_ * 2);
    short* qsc = (short*)alloc((long)B_ * H_ * S_ * DH_ * 2);
    short* ksc = (short*)alloc((long)B_ * H_ * S_ * DH_ * 2);
    short* vsT = (short*)alloc((long)B_ * DH_ * S_ * 2);
    float* rowm = (float*)alloc((long)B_ * H_ * S_ * 4);
    float* rowsum = (float*)alloc((long)B_ * H_ * S_ * 4);
    // aliases over dead regions (q_bf+k_bf are contiguous 32MB = exactly headb):
    float* headb = (float*)q_bf;   // B*H*S*DH*4 = 32MB spans q_bf..k_bf
    short* hmean = v_bf;           // B*S*DH*2 = 4MB <= 16MB

    float* attnp = (float*)d_out + (long)B_ * S_ * D_;

    auto cvtl = [&](const float* s, short* dst, long n) {
        int n4 = (int)(n / 4);
        cvt_kernel<<<(n4 + 255) / 256, 256, 0, stream>>>(s, dst, n4);
    };
    cvtl(q, q_bf, (long)B_ * S_ * D_);
    cvtl(k, k_bf, (long)B_ * S_ * D_);
    cvtl(v, v_bf, (long)B_ * S_ * D_);
    cvtl(qW, wq_bf, (long)H_ * DH_ * D_);
    cvtl(kW, wk_bf, (long)H_ * DH_ * D_);
    cvtl(vW, wv_bf, (long)DH_ * D_);
    cvtl(wH, wh_bf, (long)D_ * DH_);

    // projections
    gemm_bt<0><<<dim3(D_ / 128, S_ / 128, B_), 256, 0, stream>>>(
        q_bf, (long)S_ * D_, D_, wq_bf, 0L, D_, qb, qsc, D_);
    gemm_bt<1><<<dim3(D_ / 128, S_ / 128, B_), 256, 0, stream>>>(
        k_bf, (long)S_ * D_, D_, wk_bf, 0L, D_, kb, ksc, D_);
    gemm_bt<2><<<dim3(S_ / 128, DH_ / 128, B_), 256, 0, stream>>>(
        wv_bf, 0L, D_, v_bf, (long)S_ * D_, D_, vb, vsT, D_);

    // attention (logits + stats, then normalize-in-place + PV)
    attn_logits<<<dim3(B_ * H_, S_ / 128), 512, 0, stream>>>(qsc, ksc, attnp, rowm, rowsum);
    attn_pv<<<dim3(B_ * H_, S_ / 128), 512, 0, stream>>>(attnp, vsT, rowm, rowsum, headb);

    // mean over heads + output projection
    int n4 = B_ * S_ * DH_ / 4;
    head_reduce<<<(n4 + 255) / 256, 256, 0, stream>>>(headb, hmean, n4);
    gemm_bt<3><<<dim3(D_ / 128, S_ / 128, B_), 256, 0, stream>>>(
        hmean, (long)S_ * DH_, DH_, wh_bf, 0L, DH_, nullptr, (float*)d_out, DH_);
}